// Round 7
// baseline (255.101 us; speedup 1.0000x reference)
//
#include <hip/hip_runtime.h>

// LIF neuron scan: v = v*0.5 + x[t]; s = (v - 0.5 > 0); v -= s*0.5
// Round 6 -> 7: same as R6 (barrier-free wave-private LDS tiles + nontemporal
// output stores), fixing the compile error: __builtin_nontemporal_store needs
// a native vector type, not HIP_vector_type<float,4>. Store through
// ext_vector_type(4) float pointers (same 16B layout/alignment).
//  (1) NO BARRIERS: 256-thread blocks, wave-private 13.3KB LDS tiles; wave's
//      in-order DS pipe + compiler lgkmcnt waits give all needed ordering.
//  (2) NONTEMPORAL stores: output bypasses L2/L3 allocation -> L3 stays
//      dedicated to x instead of thrashing against the output stream.

#define T_STEPS 100
#define T_VEC   25      // float4 per row
#define WROWS   64      // rows per wave
#define HROWS   32      // rows per bounce stage
#define SLOTS   26      // float4 slots per LDS row (25 + 1 pad)
#define WAVES   4       // waves per block
#define DECAY   0.5f
#define VTH     0.5f

typedef float vfloat4 __attribute__((ext_vector_type(4)));

__device__ __forceinline__ int swz(int c4, int row) {
    // XOR low 3 bits for c4 in [0,24); c4==24 stays (in range). Per fixed c4,
    // row-groups of 8 map bijectively -> minimal bank aliasing for b128 ops.
    return (c4 < 24) ? (c4 ^ (row & 7)) : c4;
}

__global__ __launch_bounds__(256, 3) void lif_kernel(const float* __restrict__ x,
                                                     float* __restrict__ out,
                                                     int n_rows) {
    __shared__ vfloat4 tile[WAVES][HROWS * SLOTS];   // 53,248 B -> 3 blocks/CU

    const int lane = threadIdx.x & 63;
    const int wv   = threadIdx.x >> 6;
    const long long wid   = (long long)blockIdx.x * WAVES + wv;
    const long long row0  = wid * WROWS;
    const long long total_f4 = (long long)n_rows * T_VEC;

    vfloat4* tw = tile[wv];
    const vfloat4* __restrict__ xb = reinterpret_cast<const vfloat4*>(x);
    vfloat4* __restrict__ ob       = reinterpret_cast<vfloat4*>(out);

    vfloat4 buf[T_VEC];

    // ---- Input: per-wave two stages of {coalesced load -> LDS -> row grab}.
    // No barriers: wave-private tile, in-order DS + compiler lgkmcnt waits.
    #pragma unroll
    for (int stage = 0; stage < 2; ++stage) {
        const long long gbase = (row0 + stage * HROWS) * T_VEC;
        #pragma unroll
        for (int k = 0; k < 13; ++k) {
            int f = k * 64 + lane;                 // 0..831
            if (f < HROWS * T_VEC && gbase + f < total_f4) {
                vfloat4 w = xb[gbase + f];         // full-line coalesced
                int r  = f / T_VEC;
                int c4 = f % T_VEC;
                tw[r * SLOTS + swz(c4, r)] = w;
            }
        }
        if ((lane >> 5) == stage) {                // owning half-wave grabs rows
            const int r = lane & (HROWS - 1);
            #pragma unroll
            for (int j = 0; j < T_VEC; ++j)
                buf[j] = tw[r * SLOTS + swz(j, r)];
        }
    }

    // ---- Compute: 100-step LIF recurrence entirely in registers ----
    if (row0 + lane < n_rows) {
        float v = 0.0f;
        #pragma unroll
        for (int j = 0; j < T_VEC; ++j) {
            float xs[4] = {buf[j].x, buf[j].y, buf[j].z, buf[j].w};
            float ss[4];
            #pragma unroll
            for (int k = 0; k < 4; ++k) {
                // v*0.5 exact (pow2); s*0.5 in {0,0.5} exact -> bitwise == ref.
                v = v * DECAY + xs[k];
                float sk = (v - VTH > 0.0f) ? 1.0f : 0.0f;
                v -= sk * VTH;
                ss[k] = sk;
            }
            buf[j].x = ss[0]; buf[j].y = ss[1]; buf[j].z = ss[2]; buf[j].w = ss[3];
        }
    }

    // ---- Output: per-wave two stages of {row write -> coalesced nt store}.
    // Still no barriers; WAR on tile is ordered by the wave's in-order DS pipe.
    #pragma unroll
    for (int stage = 0; stage < 2; ++stage) {
        if ((lane >> 5) == stage) {
            const int r = lane & (HROWS - 1);
            #pragma unroll
            for (int j = 0; j < T_VEC; ++j)
                tw[r * SLOTS + swz(j, r)] = buf[j];
        }
        const long long gbase = (row0 + stage * HROWS) * T_VEC;
        #pragma unroll
        for (int k = 0; k < 13; ++k) {
            int f = k * 64 + lane;
            if (f < HROWS * T_VEC && gbase + f < total_f4) {
                int r  = f / T_VEC;
                int c4 = f % T_VEC;
                vfloat4 w = tw[r * SLOTS + swz(c4, r)];
                __builtin_nontemporal_store(w, &ob[gbase + f]);
            }
        }
    }
}

extern "C" void kernel_launch(void* const* d_in, const int* in_sizes, int n_in,
                              void* d_out, int out_size, void* d_ws, size_t ws_size,
                              hipStream_t stream) {
    const float* x = (const float*)d_in[0];
    float* out = (float*)d_out;

    int n_rows = in_sizes[0] / T_STEPS;                 // 32 * 16384 = 524288
    int rows_per_block = WROWS * WAVES;                 // 256
    int grid = (n_rows + rows_per_block - 1) / rows_per_block;   // 2048

    lif_kernel<<<grid, 256, 0, stream>>>(x, out, n_rows);
}